// Round 7
// baseline (105.564 us; speedup 1.0000x reference)
//
#include <hip/hip_runtime.h>
#include <math.h>

#define D 256          // feature dim (fixed by reference)
#define NREL 16        // relation count
#define CHUNK 6250     // nodes per dst-chunk (2 x f32 LDS arrays = 50 KB)
#define BPC 32         // blocks per chunk (edge-slice parallelism)

typedef float f4v __attribute__((ext_vector_type(4)));

// ---------------------------------------------------------------------------
// Kernel A: y[n][r] = dot(x[n], W[r]) for r in [0,16), xr[n] = dot(x[n], root)
// Block = 256 threads, 64 nodes. thread t: node = t&63, rgroup = t>>6.
// v3: double-buffered LDS staging — chunk c+1 global loads are issued before
// the 64-step FMA loop on chunk c, ds_write after (latency hidden under VALU).
// ---------------------------------------------------------------------------
__global__ __launch_bounds__(256) void rgcn_y_kernel(
    const float* __restrict__ x, const float* __restrict__ w,
    const float* __restrict__ root, float* __restrict__ y,
    float* __restrict__ xr, int n)
{
    __shared__ float lds[2][64 * 65];
    const int t = threadIdx.x;
    const int nl = t & 63;
    const int rg = __builtin_amdgcn_readfirstlane(t >> 6);  // wave-uniform
    const int node = blockIdx.x * 64 + nl;
    const int base = blockIdx.x * 64;

    const float* w0 = w + (size_t)(rg * 4 + 0) * D;
    const float* w1 = w + (size_t)(rg * 4 + 1) * D;
    const float* w2 = w + (size_t)(rg * 4 + 2) * D;
    const float* w3 = w + (size_t)(rg * 4 + 3) * D;
    const float* w4 = (rg == 3) ? root : w0;  // root handled by rgroup 3

    float acc0 = 0.f, acc1 = 0.f, acc2 = 0.f, acc3 = 0.f, accR = 0.f;

    // fixed per-thread staging geometry: flat = j*256+t
    int snlj[4], f4j[4];
    #pragma unroll
    for (int j = 0; j < 4; ++j) {
        int flat = j * 256 + t;
        snlj[j] = flat >> 4;     // staged node local 0..63
        f4j[j]  = flat & 15;     // float4 index within 64-float chunk
    }

    float4 vv[4];
    // ---- prologue: load + stage chunk 0 ----
    #pragma unroll
    for (int j = 0; j < 4; ++j) {
        int gn = base + snlj[j];
        vv[j] = make_float4(0.f, 0.f, 0.f, 0.f);
        if (gn < n)
            vv[j] = *reinterpret_cast<const float4*>(
                        x + (size_t)gn * D + f4j[j] * 4);
    }
    #pragma unroll
    for (int j = 0; j < 4; ++j) {
        int a = snlj[j] * 65 + f4j[j] * 4;
        lds[0][a + 0] = vv[j].x; lds[0][a + 1] = vv[j].y;
        lds[0][a + 2] = vv[j].z; lds[0][a + 3] = vv[j].w;
    }
    __syncthreads();

    #pragma unroll
    for (int c = 0; c < 4; ++c) {
        // issue next chunk's global loads (latency hides under the FMA loop)
        if (c < 3) {
            #pragma unroll
            for (int j = 0; j < 4; ++j) {
                int gn = base + snlj[j];
                vv[j] = make_float4(0.f, 0.f, 0.f, 0.f);
                if (gn < n)
                    vv[j] = *reinterpret_cast<const float4*>(
                                x + (size_t)gn * D + (c + 1) * 64 + f4j[j] * 4);
            }
        }

        const float* wc0 = w0 + c * 64;
        const float* wc1 = w1 + c * 64;
        const float* wc2 = w2 + c * 64;
        const float* wc3 = w3 + c * 64;
        const float* wc4 = w4 + c * 64;
        #pragma unroll
        for (int d = 0; d < 64; ++d) {
            float xv = lds[c & 1][nl * 65 + d];
            acc0 = fmaf(xv, wc0[d], acc0);
            acc1 = fmaf(xv, wc1[d], acc1);
            acc2 = fmaf(xv, wc2[d], acc2);
            acc3 = fmaf(xv, wc3[d], acc3);
            accR = fmaf(xv, wc4[d], accR);
        }

        if (c < 3) {
            __syncthreads();   // everyone done reading buf[(c+1)&1] (iter c-1)
            #pragma unroll
            for (int j = 0; j < 4; ++j) {
                int a = snlj[j] * 65 + f4j[j] * 4;
                lds[(c + 1) & 1][a + 0] = vv[j].x;
                lds[(c + 1) & 1][a + 1] = vv[j].y;
                lds[(c + 1) & 1][a + 2] = vv[j].z;
                lds[(c + 1) & 1][a + 3] = vv[j].w;
            }
            __syncthreads();
        }
    }

    if (node < n) {
        float4 o; o.x = acc0; o.y = acc1; o.z = acc2; o.w = acc3;
        *reinterpret_cast<float4*>(y + (size_t)node * NREL + rg * 4) = o;
        if (rg == 3) xr[node] = accR;
    }
}

// ---------------------------------------------------------------------------
// Kernel B: chunked edge scan, LDS accumulation, zero global atomics.
// Unconditional int4 loads of dst/src/et (3 independent vector loads per
// 4-edge group -> deep memory-level parallelism).
// ---------------------------------------------------------------------------
__global__ __launch_bounds__(1024) void rgcn_edge_scan_kernel(
    const int* __restrict__ src, const int* __restrict__ dst,
    const int* __restrict__ et, const float* __restrict__ y,
    float2* __restrict__ partial, int e, int sl)
{
    __shared__ float lsum[CHUNK];
    __shared__ float lcnt[CHUNK];
    const int t = threadIdx.x;
    const int c = blockIdx.x / BPC;
    const int b = blockIdx.x % BPC;
    const int base = c * CHUNK;

    for (int j = t; j < CHUNK; j += 1024) { lsum[j] = 0.f; lcnt[j] = 0.f; }
    __syncthreads();

    const int slice0 = b * sl;
    const int rem = e - slice0;
    if (rem > 0) {
        const int gmax = (min(sl, rem) + 3) >> 2;   // int4 groups in slice
        for (int g = t; g < gmax; g += 1024) {
            int idx = slice0 + g * 4;
            if (idx + 3 < e) {
                int4 d4 = *reinterpret_cast<const int4*>(dst + idx);
                int4 s4 = *reinterpret_cast<const int4*>(src + idx);
                int4 r4 = *reinterpret_cast<const int4*>(et + idx);
                int loc0 = d4.x - base, loc1 = d4.y - base;
                int loc2 = d4.z - base, loc3 = d4.w - base;
                if ((unsigned)loc0 < (unsigned)CHUNK) {
                    atomicAdd(&lsum[loc0], y[(size_t)s4.x * NREL + r4.x]);
                    atomicAdd(&lcnt[loc0], 1.0f);
                }
                if ((unsigned)loc1 < (unsigned)CHUNK) {
                    atomicAdd(&lsum[loc1], y[(size_t)s4.y * NREL + r4.y]);
                    atomicAdd(&lcnt[loc1], 1.0f);
                }
                if ((unsigned)loc2 < (unsigned)CHUNK) {
                    atomicAdd(&lsum[loc2], y[(size_t)s4.z * NREL + r4.z]);
                    atomicAdd(&lcnt[loc2], 1.0f);
                }
                if ((unsigned)loc3 < (unsigned)CHUNK) {
                    atomicAdd(&lsum[loc3], y[(size_t)s4.w * NREL + r4.w]);
                    atomicAdd(&lcnt[loc3], 1.0f);
                }
            } else {
                for (int k = idx; k < e; ++k) {
                    int loc = dst[k] - base;
                    if ((unsigned)loc < (unsigned)CHUNK) {
                        atomicAdd(&lsum[loc], y[(size_t)src[k] * NREL + et[k]]);
                        atomicAdd(&lcnt[loc], 1.0f);
                    }
                }
            }
        }
    }
    __syncthreads();

    float2* p = partial + ((size_t)(c * BPC + b)) * CHUNK;
    for (int j = t; j < CHUNK; j += 1024)
        p[j] = make_float2(lsum[j], lcnt[j]);
}

// ---------------------------------------------------------------------------
// Kernel C (fused finish), 32 nodes/block:
//   phase 1 (ALL threads): thread t reduces 4 partials of node t&31
//                          (b-group t>>5), LDS-atomic combine;
//                          then 32 threads do tanh -> sc[] + out_score.
//   phase 2 (all):  x_out = x * score, nontemporal float4 stores.
// ---------------------------------------------------------------------------
__global__ __launch_bounds__(256) void rgcn_finish_kernel(
    const float2* __restrict__ partial, const float* __restrict__ xr,
    const float* __restrict__ bias, const float* __restrict__ x,
    float* __restrict__ out_x, float* __restrict__ out_score, int n)
{
    __shared__ float ssum[32], scnt[32], sc[32];
    const int t = threadIdx.x;
    const int base = blockIdx.x * 32;

    if (t < 32) { ssum[t] = 0.f; scnt[t] = 0.f; }
    __syncthreads();

    {
        int nl = t & 31;
        int bg = t >> 5;                 // 0..7, covers BPC=32 in 4s
        int node = base + nl;
        float s = 0.f, cN = 0.f;
        if (node < n) {
            int c = node / CHUNK;
            int j = node - c * CHUNK;
            const float2* p = partial + (size_t)c * BPC * CHUNK + j;
            #pragma unroll
            for (int b = 0; b < 4; ++b) {
                float2 v = p[(size_t)(bg * 4 + b) * CHUNK];
                s += v.x; cN += v.y;
            }
        }
        atomicAdd(&ssum[nl], s);
        atomicAdd(&scnt[nl], cN);
    }
    __syncthreads();

    if (t < 32) {
        int node = base + t;
        if (node < n) {
            float m = ssum[t] / fmaxf(scnt[t], 1.0f);
            float v = tanhf(m + xr[node] + bias[0]);
            sc[t] = v;
            out_score[node] = v;
        }
    }
    __syncthreads();

    #pragma unroll
    for (int k = 0; k < 8; ++k) {
        int nl = k * 4 + (t >> 6);       // node local 0..31
        int f4 = t & 63;                 // float4 index in row
        int node = base + nl;
        if (node < n) {
            float s = sc[nl];
            float4 v = *reinterpret_cast<const float4*>(
                           x + (size_t)node * D + f4 * 4);
            v.x *= s; v.y *= s; v.z *= s; v.w *= s;
            f4v vo = {v.x, v.y, v.z, v.w};
            __builtin_nontemporal_store(
                vo, (f4v*)(out_x + (size_t)node * D + f4 * 4));
        }
    }
}

// --------------------- fallback path (scratch in out tail) -----------------
__global__ __launch_bounds__(256) void rgcn_reduce_score_kernel(
    const float2* __restrict__ partial, const float* __restrict__ xr,
    const float* __restrict__ bias, float* __restrict__ score, int n)
{
    int i = blockIdx.x * 256 + threadIdx.x;
    if (i < n) {
        int c = i / CHUNK;
        int j = i - c * CHUNK;
        const float2* p = partial + (size_t)c * BPC * CHUNK + j;
        float s = 0.f, cN = 0.f;
        #pragma unroll 8
        for (int b = 0; b < BPC; ++b) {
            float2 v = p[(size_t)b * CHUNK];
            s += v.x; cN += v.y;
        }
        float m = s / fmaxf(cN, 1.0f);
        score[i] = tanhf(m + xr[i] + bias[0]);
    }
}

__global__ __launch_bounds__(256) void rgcn_scale_kernel(
    const float* __restrict__ x, const float* __restrict__ score,
    float* __restrict__ xo, int n)
{
    int gid = blockIdx.x * 256 + threadIdx.x;
    int node = gid >> 6;
    int f4 = gid & 63;
    if (node < n) {
        float s = score[node];
        float4 v = *reinterpret_cast<const float4*>(
                       x + (size_t)node * D + f4 * 4);
        v.x *= s; v.y *= s; v.z *= s; v.w *= s;
        *reinterpret_cast<float4*>(xo + (size_t)node * D + f4 * 4) = v;
    }
}

extern "C" void kernel_launch(void* const* d_in, const int* in_sizes, int n_in,
                              void* d_out, int out_size, void* d_ws, size_t ws_size,
                              hipStream_t stream)
{
    const float* x    = (const float*)d_in[0];
    const int*   ei   = (const int*)d_in[1];   // (2, E): src then dst
    const int*   et   = (const int*)d_in[2];
    const float* w    = (const float*)d_in[3]; // (R, D, 1) -> flat r*D+d
    const float* root = (const float*)d_in[4]; // (D, 1)    -> flat d
    const float* bias = (const float*)d_in[5];

    const int n = in_sizes[0] / D;   // 50000
    const int e = in_sizes[2];       // 800000

    float* out       = (float*)d_out;
    float* out_x     = out;                       // n*D floats
    float* out_score = out + (size_t)n * D;       // n floats

    const int C = (n + CHUNK - 1) / CHUNK;        // 8 for n=50000
    const int sl = ((((e + BPC - 1) / BPC) + 3) & ~3);  // slice len, mult of 4

    // Scratch: partials (C*BPC*CHUNK float2) | y (16n) | xr (n)
    const size_t part_f = (size_t)C * BPC * CHUNK * 2;   // floats
    const size_t need_f = part_f + (size_t)n * (NREL + 1);
    const bool use_ws = (ws_size >= need_f * sizeof(float));

    float* sb;
    if (use_ws)
        sb = (float*)d_ws;
    else {
        size_t ts = (((size_t)n * D - need_f) & ~(size_t)1);  // 8B-align
        sb = out_x + ts;
    }
    float2* partial = (float2*)sb;
    float*  y  = sb + part_f;
    float*  xr = y + (size_t)n * NREL;

    dim3 blk(256);
    rgcn_y_kernel<<<dim3((n + 63) / 64), blk, 0, stream>>>(x, w, root, y, xr, n);

    rgcn_edge_scan_kernel<<<dim3(C * BPC), dim3(1024), 0, stream>>>(
        ei, ei + e, et, y, partial, e, sl);

    if (use_ws) {
        rgcn_finish_kernel<<<dim3((n + 31) / 32), blk, 0, stream>>>(
            partial, xr, bias, x, out_x, out_score, n);
    } else {
        rgcn_reduce_score_kernel<<<dim3((n + 255) / 256), blk, 0, stream>>>(
            partial, xr, bias, out_score, n);
        rgcn_scale_kernel<<<dim3((int)(((size_t)n * 64 + 255) / 256)), blk, 0, stream>>>(
            x, out_score, out_x, n);
    }
}

// Round 8
// 61.225 us; speedup vs baseline: 1.7242x; 1.7242x over previous
//
#include <hip/hip_runtime.h>
#include <math.h>

#define D 256          // feature dim (fixed by reference)
#define NREL 16        // relation count
#define CHUNK 6250     // nodes per dst-chunk (2 x f32 LDS arrays = 50 KB)
#define BPC 32         // blocks per chunk (edge-slice parallelism)
#define LDST 129       // LDS row stride for the 64x128 x-tile (129%32==1 -> conflict-free)

typedef float f4v __attribute__((ext_vector_type(4)));

// ---------------------------------------------------------------------------
// Kernel A v4: y[n][r] = dot(x[n], W[r]) r<16, xr[n] = dot(x[n], root).
// Block = 256 threads / 64 nodes; thread t: node = t&63, rgroup = t>>6 owns
// 4 W-rows (wave-uniform -> scalar loads). Two 128-d halves; each stage phase
// posts 8 independent float4 loads/thread (32 KB/block in flight -> MLP),
// 33 KB LDS tile (4 blocks/CU), 3 barriers total, no register prefetch.
// ---------------------------------------------------------------------------
__global__ __launch_bounds__(256) void rgcn_y_kernel(
    const float* __restrict__ x, const float* __restrict__ w,
    const float* __restrict__ root, float* __restrict__ y,
    float* __restrict__ xr, int n)
{
    __shared__ float lds[64 * LDST];   // 33 KB
    const int t = threadIdx.x;
    const int nl = t & 63;
    const int rg = __builtin_amdgcn_readfirstlane(t >> 6);  // wave-uniform
    const int node = blockIdx.x * 64 + nl;
    const int base = blockIdx.x * 64;

    const float* w0 = w + (size_t)(rg * 4 + 0) * D;
    const float* w1 = w + (size_t)(rg * 4 + 1) * D;
    const float* w2 = w + (size_t)(rg * 4 + 2) * D;
    const float* w3 = w + (size_t)(rg * 4 + 3) * D;
    const float* w4 = (rg == 3) ? root : w0;  // root handled by rgroup 3

    float acc0 = 0.f, acc1 = 0.f, acc2 = 0.f, acc3 = 0.f, accR = 0.f;

    #pragma unroll
    for (int h = 0; h < 2; ++h) {   // two 128-d halves
        // ---- stage 64 nodes x 128 d: 8 coalesced float4 per thread ----
        #pragma unroll
        for (int k = 0; k < 8; ++k) {
            int flat = k * 256 + t;       // float4 slot 0..2047
            int snl  = flat >> 5;         // staged node local 0..63
            int f4i  = flat & 31;         // float4 idx within 128-d half
            int gn   = base + snl;
            float4 v = make_float4(0.f, 0.f, 0.f, 0.f);
            if (gn < n)
                v = *reinterpret_cast<const float4*>(
                        x + (size_t)gn * D + h * 128 + f4i * 4);
            int a = snl * LDST + f4i * 4;
            lds[a + 0] = v.x; lds[a + 1] = v.y;
            lds[a + 2] = v.z; lds[a + 3] = v.w;
        }
        __syncthreads();

        const float* h0 = w0 + h * 128;
        const float* h1 = w1 + h * 128;
        const float* h2 = w2 + h * 128;
        const float* h3 = w3 + h * 128;
        const float* h4 = w4 + h * 128;
        #pragma unroll 16
        for (int d = 0; d < 128; ++d) {
            float xv = lds[nl * LDST + d];
            acc0 = fmaf(xv, h0[d], acc0);
            acc1 = fmaf(xv, h1[d], acc1);
            acc2 = fmaf(xv, h2[d], acc2);
            acc3 = fmaf(xv, h3[d], acc3);
            accR = fmaf(xv, h4[d], accR);
        }
        if (h == 0) __syncthreads();   // tile reuse barrier
    }

    if (node < n) {
        float4 o; o.x = acc0; o.y = acc1; o.z = acc2; o.w = acc3;
        *reinterpret_cast<float4*>(y + (size_t)node * NREL + rg * 4) = o;
        if (rg == 3) xr[node] = accR;
    }
}

// ---------------------------------------------------------------------------
// Kernel B: chunked edge scan, LDS accumulation, zero global atomics.
// Unconditional int4 loads of dst/src/et (3 independent vector loads per
// 4-edge group -> deep memory-level parallelism).
// ---------------------------------------------------------------------------
__global__ __launch_bounds__(1024) void rgcn_edge_scan_kernel(
    const int* __restrict__ src, const int* __restrict__ dst,
    const int* __restrict__ et, const float* __restrict__ y,
    float2* __restrict__ partial, int e, int sl)
{
    __shared__ float lsum[CHUNK];
    __shared__ float lcnt[CHUNK];
    const int t = threadIdx.x;
    const int c = blockIdx.x / BPC;
    const int b = blockIdx.x % BPC;
    const int base = c * CHUNK;

    for (int j = t; j < CHUNK; j += 1024) { lsum[j] = 0.f; lcnt[j] = 0.f; }
    __syncthreads();

    const int slice0 = b * sl;
    const int rem = e - slice0;
    if (rem > 0) {
        const int gmax = (min(sl, rem) + 3) >> 2;   // int4 groups in slice
        for (int g = t; g < gmax; g += 1024) {
            int idx = slice0 + g * 4;
            if (idx + 3 < e) {
                int4 d4 = *reinterpret_cast<const int4*>(dst + idx);
                int4 s4 = *reinterpret_cast<const int4*>(src + idx);
                int4 r4 = *reinterpret_cast<const int4*>(et + idx);
                int loc0 = d4.x - base, loc1 = d4.y - base;
                int loc2 = d4.z - base, loc3 = d4.w - base;
                if ((unsigned)loc0 < (unsigned)CHUNK) {
                    atomicAdd(&lsum[loc0], y[(size_t)s4.x * NREL + r4.x]);
                    atomicAdd(&lcnt[loc0], 1.0f);
                }
                if ((unsigned)loc1 < (unsigned)CHUNK) {
                    atomicAdd(&lsum[loc1], y[(size_t)s4.y * NREL + r4.y]);
                    atomicAdd(&lcnt[loc1], 1.0f);
                }
                if ((unsigned)loc2 < (unsigned)CHUNK) {
                    atomicAdd(&lsum[loc2], y[(size_t)s4.z * NREL + r4.z]);
                    atomicAdd(&lcnt[loc2], 1.0f);
                }
                if ((unsigned)loc3 < (unsigned)CHUNK) {
                    atomicAdd(&lsum[loc3], y[(size_t)s4.w * NREL + r4.w]);
                    atomicAdd(&lcnt[loc3], 1.0f);
                }
            } else {
                for (int k = idx; k < e; ++k) {
                    int loc = dst[k] - base;
                    if ((unsigned)loc < (unsigned)CHUNK) {
                        atomicAdd(&lsum[loc], y[(size_t)src[k] * NREL + et[k]]);
                        atomicAdd(&lcnt[loc], 1.0f);
                    }
                }
            }
        }
    }
    __syncthreads();

    float2* p = partial + ((size_t)(c * BPC + b)) * CHUNK;
    for (int j = t; j < CHUNK; j += 1024)
        p[j] = make_float2(lsum[j], lcnt[j]);
}

// ---------------------------------------------------------------------------
// Kernel C (fused finish), 32 nodes/block:
//   phase 1 (ALL threads): thread t reduces 4 partials of node t&31
//                          (b-group t>>5), LDS-atomic combine;
//                          then 32 threads do tanh -> sc[] + out_score.
//   phase 2 (all):  x_out = x * score, nontemporal float4 stores.
// ---------------------------------------------------------------------------
__global__ __launch_bounds__(256) void rgcn_finish_kernel(
    const float2* __restrict__ partial, const float* __restrict__ xr,
    const float* __restrict__ bias, const float* __restrict__ x,
    float* __restrict__ out_x, float* __restrict__ out_score, int n)
{
    __shared__ float ssum[32], scnt[32], sc[32];
    const int t = threadIdx.x;
    const int base = blockIdx.x * 32;

    if (t < 32) { ssum[t] = 0.f; scnt[t] = 0.f; }
    __syncthreads();

    {
        int nl = t & 31;
        int bg = t >> 5;                 // 0..7, covers BPC=32 in 4s
        int node = base + nl;
        float s = 0.f, cN = 0.f;
        if (node < n) {
            int c = node / CHUNK;
            int j = node - c * CHUNK;
            const float2* p = partial + (size_t)c * BPC * CHUNK + j;
            #pragma unroll
            for (int b = 0; b < 4; ++b) {
                float2 v = p[(size_t)(bg * 4 + b) * CHUNK];
                s += v.x; cN += v.y;
            }
        }
        atomicAdd(&ssum[nl], s);
        atomicAdd(&scnt[nl], cN);
    }
    __syncthreads();

    if (t < 32) {
        int node = base + t;
        if (node < n) {
            float m = ssum[t] / fmaxf(scnt[t], 1.0f);
            float v = tanhf(m + xr[node] + bias[0]);
            sc[t] = v;
            out_score[node] = v;
        }
    }
    __syncthreads();

    #pragma unroll
    for (int k = 0; k < 8; ++k) {
        int nl = k * 4 + (t >> 6);       // node local 0..31
        int f4 = t & 63;                 // float4 index in row
        int node = base + nl;
        if (node < n) {
            float s = sc[nl];
            float4 v = *reinterpret_cast<const float4*>(
                           x + (size_t)node * D + f4 * 4);
            v.x *= s; v.y *= s; v.z *= s; v.w *= s;
            f4v vo = {v.x, v.y, v.z, v.w};
            __builtin_nontemporal_store(
                vo, (f4v*)(out_x + (size_t)node * D + f4 * 4));
        }
    }
}

// --------------------- fallback path (scratch in out tail) -----------------
__global__ __launch_bounds__(256) void rgcn_reduce_score_kernel(
    const float2* __restrict__ partial, const float* __restrict__ xr,
    const float* __restrict__ bias, float* __restrict__ score, int n)
{
    int i = blockIdx.x * 256 + threadIdx.x;
    if (i < n) {
        int c = i / CHUNK;
        int j = i - c * CHUNK;
        const float2* p = partial + (size_t)c * BPC * CHUNK + j;
        float s = 0.f, cN = 0.f;
        #pragma unroll 8
        for (int b = 0; b < BPC; ++b) {
            float2 v = p[(size_t)b * CHUNK];
            s += v.x; cN += v.y;
        }
        float m = s / fmaxf(cN, 1.0f);
        score[i] = tanhf(m + xr[i] + bias[0]);
    }
}

__global__ __launch_bounds__(256) void rgcn_scale_kernel(
    const float* __restrict__ x, const float* __restrict__ score,
    float* __restrict__ xo, int n)
{
    int gid = blockIdx.x * 256 + threadIdx.x;
    int node = gid >> 6;
    int f4 = gid & 63;
    if (node < n) {
        float s = score[node];
        float4 v = *reinterpret_cast<const float4*>(
                       x + (size_t)node * D + f4 * 4);
        v.x *= s; v.y *= s; v.z *= s; v.w *= s;
        *reinterpret_cast<float4*>(xo + (size_t)node * D + f4 * 4) = v;
    }
}

extern "C" void kernel_launch(void* const* d_in, const int* in_sizes, int n_in,
                              void* d_out, int out_size, void* d_ws, size_t ws_size,
                              hipStream_t stream)
{
    const float* x    = (const float*)d_in[0];
    const int*   ei   = (const int*)d_in[1];   // (2, E): src then dst
    const int*   et   = (const int*)d_in[2];
    const float* w    = (const float*)d_in[3]; // (R, D, 1) -> flat r*D+d
    const float* root = (const float*)d_in[4]; // (D, 1)    -> flat d
    const float* bias = (const float*)d_in[5];

    const int n = in_sizes[0] / D;   // 50000
    const int e = in_sizes[2];       // 800000

    float* out       = (float*)d_out;
    float* out_x     = out;                       // n*D floats
    float* out_score = out + (size_t)n * D;       // n floats

    const int C = (n + CHUNK - 1) / CHUNK;        // 8 for n=50000
    const int sl = ((((e + BPC - 1) / BPC) + 3) & ~3);  // slice len, mult of 4

    // Scratch: partials (C*BPC*CHUNK float2) | y (16n) | xr (n)
    const size_t part_f = (size_t)C * BPC * CHUNK * 2;   // floats
    const size_t need_f = part_f + (size_t)n * (NREL + 1);
    const bool use_ws = (ws_size >= need_f * sizeof(float));

    float* sb;
    if (use_ws)
        sb = (float*)d_ws;
    else {
        size_t ts = (((size_t)n * D - need_f) & ~(size_t)1);  // 8B-align
        sb = out_x + ts;
    }
    float2* partial = (float2*)sb;
    float*  y  = sb + part_f;
    float*  xr = y + (size_t)n * NREL;

    dim3 blk(256);
    rgcn_y_kernel<<<dim3((n + 63) / 64), blk, 0, stream>>>(x, w, root, y, xr, n);

    rgcn_edge_scan_kernel<<<dim3(C * BPC), dim3(1024), 0, stream>>>(
        ei, ei + e, et, y, partial, e, sl);

    if (use_ws) {
        rgcn_finish_kernel<<<dim3((n + 31) / 32), blk, 0, stream>>>(
            partial, xr, bias, x, out_x, out_score, n);
    } else {
        rgcn_reduce_score_kernel<<<dim3((n + 255) / 256), blk, 0, stream>>>(
            partial, xr, bias, out_score, n);
        rgcn_scale_kernel<<<dim3((int)(((size_t)n * 64 + 255) / 256)), blk, 0, stream>>>(
            x, out_score, out_x, n);
    }
}